// Round 11
// baseline (62.176 us; speedup 1.0000x reference)
//
#include <hip/hip_runtime.h>
#include <hip/hip_bf16.h>

typedef short short8 __attribute__((ext_vector_type(8)));
typedef float f32x4 __attribute__((ext_vector_type(4)));

__device__ inline unsigned short f2bf(float f) {
    unsigned u = __builtin_bit_cast(unsigned, f);
    u += 0x7FFFu + ((u >> 16) & 1u);          // round-to-nearest-even
    return (unsigned short)(u >> 16);
}

// ---------------------------------------------------------------------------
// Fully fused single kernel: out[n][d] = sum_c X[n][c] * Wm[d][c] + bm[d],
//   Wm = 0.25*sum_h Wv[h*64+d][c], bm = 0.25*sum_h bv[h*64+d].
// Block = 512 threads = 8 waves, owns 128 rows (wave w: rows [b*128+w*16,+16)).
// Phase 0: issue this wave's X loads (first K-chunk) so HBM latency hides
//          under prep; build B-fragment tile Bs (32 KB) from Wv via L2
//          (200 MB aggregate L2 traffic, ~6 us chip-wide, overlapped).
// Phase 1: register-lean 2-deep K-pipeline (R10) with B from LDS.
// Phase 2: LDS-bounce epilogue -> contiguous 1 KB stores (R9).
// ---------------------------------------------------------------------------
__global__ __launch_bounds__(512)
void k_fused(const float* __restrict__ X, const float* __restrict__ Wv,
             const float* __restrict__ bv, float* __restrict__ out, int N)
{
    __shared__ unsigned short Bs[16384];            // 32 KB B fragments
    __shared__ float Xt[8][16 * 68];                // 34 KB epilogue tiles

    const int t = threadIdx.x;
    const int wave = t >> 6, lane = t & 63;
    const int col_lo = lane & 15, kgrp = lane >> 4;
    const int rowbase = blockIdx.x * 128 + wave * 16;

    const int arow0 = rowbase + (lane & 15);
    const int arow = arow0 < N ? arow0 : N - 1;     // clamp tail rows
    const float* xrow = X + (size_t)arow * 256 + kgrp * 8;

    // issue first X chunk early (HBM latency hides under prep)
    f32x4 c0 = *(const f32x4*)(xrow);
    f32x4 c1 = *(const f32x4*)(xrow + 4);

    // ---- prep: Wm -> Bs fragments ----
    // thread t: d = t>>3 (0..63), cs = t&7 (32-col slice); per 8-col group g:
    // lane_b = (d&15) + 16*g, fragment addr = (((d>>4)*8 + cs)*64 + lane_b)*8
    {
        const int d = t >> 3, cs = t & 7;
        const float* wr0 = Wv + (size_t)d * 256 + cs * 32;
        const float* wr1 = wr0 + 64 * 256;
        const float* wr2 = wr0 + 128 * 256;
        const float* wr3 = wr0 + 192 * 256;
        const int fbase = (((d >> 4) * 8 + cs) * 64 + (d & 15)) * 8;
#pragma unroll
        for (int g = 0; g < 4; ++g) {
            const f32x4 a0 = *(const f32x4*)(wr0 + g * 8);
            const f32x4 a1 = *(const f32x4*)(wr0 + g * 8 + 4);
            const f32x4 b0 = *(const f32x4*)(wr1 + g * 8);
            const f32x4 b1 = *(const f32x4*)(wr1 + g * 8 + 4);
            const f32x4 d0 = *(const f32x4*)(wr2 + g * 8);
            const f32x4 d1 = *(const f32x4*)(wr2 + g * 8 + 4);
            const f32x4 e0 = *(const f32x4*)(wr3 + g * 8);
            const f32x4 e1 = *(const f32x4*)(wr3 + g * 8 + 4);
            short8 p;
#pragma unroll
            for (int j = 0; j < 4; ++j)
                p[j] = (short)f2bf(0.25f * (a0[j] + b0[j] + d0[j] + e0[j]));
#pragma unroll
            for (int j = 0; j < 4; ++j)
                p[4 + j] = (short)f2bf(0.25f * (a1[j] + b1[j] + d1[j] + e1[j]));
            *(short8*)&Bs[fbase + g * 16 * 8] = p;
        }
    }

    // bias per-lane (bv is 1 KB, L1/L2-hot across all blocks)
    float bias[4];
#pragma unroll
    for (int ct = 0; ct < 4; ++ct) {
        const int c = ct * 16 + col_lo;
        bias[ct] = 0.25f * (bv[c] + bv[64 + c] + bv[128 + c] + bv[192 + c]);
    }

    __syncthreads();                                // Bs ready

    // ---- main: 2-deep K-pipeline, B from LDS ----
    f32x4 acc[4] = {};
#pragma unroll
    for (int kc = 0; kc < 8; ++kc) {
        f32x4 n0, n1;
        if (kc < 7) {
            n0 = *(const f32x4*)(xrow + (kc + 1) * 32);
            n1 = *(const f32x4*)(xrow + (kc + 1) * 32 + 4);
        }
        short8 a;
        a[0] = (short)f2bf(c0[0]); a[1] = (short)f2bf(c0[1]);
        a[2] = (short)f2bf(c0[2]); a[3] = (short)f2bf(c0[3]);
        a[4] = (short)f2bf(c1[0]); a[5] = (short)f2bf(c1[1]);
        a[6] = (short)f2bf(c1[2]); a[7] = (short)f2bf(c1[3]);
#pragma unroll
        for (int ct = 0; ct < 4; ++ct) {
            const short8 b = *(const short8*)&Bs[((ct * 8 + kc) * 64 + lane) * 8];
            acc[ct] = __builtin_amdgcn_mfma_f32_16x16x32_bf16(a, b, acc[ct], 0, 0, 0);
        }
        if (kc < 7) { c0 = n0; c1 = n1; }
    }

    // ---- epilogue: acc -> LDS (C/D: col=lane&15, row=(lane>>4)*4+reg) ----
    float* wtile = &Xt[wave][0];
#pragma unroll
    for (int ct = 0; ct < 4; ++ct) {
#pragma unroll
        for (int r = 0; r < 4; ++r)
            wtile[(kgrp * 4 + r) * 68 + ct * 16 + col_lo] = acc[ct][r] + bias[ct];
    }
    // same-wave LDS dependency only (no barrier)

    // coalesced stores: instr s = rows [s*4,s*4+4) x all 64 cols = 1 KB
#pragma unroll
    for (int s = 0; s < 4; ++s) {
        const int rho = s * 4 + (lane >> 4);
        const int c4 = lane & 15;
        const f32x4 v = *(const f32x4*)&wtile[rho * 68 + c4 * 4];
        const int grow = rowbase + rho;
        if (grow < N)
            *(f32x4*)&out[(size_t)grow * 64 + c4 * 4] = v;
    }
}

extern "C" void kernel_launch(void* const* d_in, const int* in_sizes, int n_in,
                              void* d_out, int out_size, void* d_ws, size_t ws_size,
                              hipStream_t stream)
{
    const float* sx = (const float*)d_in[1];        // source_input
    const float* Wv = (const float*)d_in[6];
    const float* bv = (const float*)d_in[7];
    float* out = (float*)d_out;

    const int N = in_sizes[0] / 256;
    const int nblk = (N + 127) / 128;

    k_fused<<<nblk, 512, 0, stream>>>(sx, Wv, bv, out, N);
}